// Round 5
// baseline (503.105 us; speedup 1.0000x reference)
//
#include <hip/hip_runtime.h>

static constexpr int IMG  = 2048;   // H = W
static constexpr int CH   = 3;
static constexpr int KS   = 25;     // PSF size
static constexpr int HALO = 12;     // KS/2
static constexpr int DN   = 512;    // downsampled size (IMG/4)
static constexpr int PD   = 18;     // taps, downsample (kw=16 -> ceil+2)
static constexpr int PU   = 6;      // taps, upsample  (kw=4  -> ceil+2)
static constexpr float LAM = 0.1f;

// ---------------------------------------------------------------------------
// Bicubic resize weight tables (matches MATLAB-style imresize in the ref).
// ---------------------------------------------------------------------------
__device__ __forceinline__ double cubic_d(double x) {
  double ax = fabs(x), ax2 = ax * ax, ax3 = ax2 * ax;
  if (ax <= 1.0) return 1.5 * ax3 - 2.5 * ax2 + 1.0;
  if (ax <= 2.0) return -0.5 * ax3 + 2.5 * ax2 - 4.0 * ax + 2.0;
  return 0.0;
}

__global__ void build_tables(float* dwW, int* dwI, float* uwW, int* uwI) {
  int i = blockIdx.x * blockDim.x + threadIdx.x;
  if (i < DN) {
    const double scale = 0.25;
    double u = (double)(i + 1) / scale + 0.5 * (1.0 - 1.0 / scale);
    double left = floor(u - 8.0);
    double w[PD]; int id[PD]; double s = 0.0;
    for (int p = 0; p < PD; ++p) {
      double ind = left + p;
      w[p] = scale * cubic_d(scale * (u - ind));
      s += w[p];
      long long m = ((long long)ind - 1) % (2 * IMG);
      if (m < 0) m += 2 * IMG;
      id[p] = (m < IMG) ? (int)m : (int)(2 * IMG - 1 - m);
    }
    for (int p = 0; p < PD; ++p) {
      dwW[i * PD + p] = (float)(w[p] / s);
      dwI[i * PD + p] = id[p];
    }
  }
  if (i < IMG) {
    const double scale = 4.0;
    double u = (double)(i + 1) / scale + 0.5 * (1.0 - 1.0 / scale);
    double left = floor(u - 2.0);
    double w[PU]; int id[PU]; double s = 0.0;
    for (int p = 0; p < PU; ++p) {
      double ind = left + p;
      w[p] = cubic_d(u - ind);
      s += w[p];
      long long m = ((long long)ind - 1) % (2 * DN);
      if (m < 0) m += 2 * DN;
      id[p] = (m < DN) ? (int)m : (int)(2 * DN - 1 - m);
    }
    for (int p = 0; p < PU; ++p) {
      uwW[i * PU + p] = (float)(w[p] / s);
      uwI[i * PU + p] = id[p];
    }
  }
}

// ---------------------------------------------------------------------------
// 25x25 circular cross-correlation, fp32.
// FLIP=1: weight = k[24-ky][24-kx], FLIP=0: weight = k[ky][kx].
// Tile: 128x64 outputs / 256 threads; each thread: 8x * 4y outputs.
// LDS: 88x160 (stride 160 == 0 mod 32 banks) with XOR swizzle
// col ^= ((r>>2)&7)<<2 -> wave64 ds_read_b128 hits every bank exactly 8x
// (minimum).  >>2 because thread rows are y-stride-4.
// Explicit ping-pong strip prefetch (bufA/bufB, static indexing) hides
// ds_read latency under the 800-FMA blocks at 2 waves/SIMD occupancy.
// ---------------------------------------------------------------------------
template <int FLIP>
__global__ __launch_bounds__(256, 2) void corr25(const float* __restrict__ src,
                                                 const float* __restrict__ kwp,
                                                 float* __restrict__ dst) {
  constexpr int TW = 128, TH = 64;
  constexpr int SW = 160;             // padded staged width (152 valid cols)
  constexpr int SH = TH + KS - 1;     // 88
  constexpr int CHUNKS = 152 / 4;     // 38 float4 chunks per staged row
  constexpr int NSTRIP = 4 + KS - 1;  // 28 staged row-strips per thread
  __shared__ float tile[SH][SW];      // 56320 B -> 2 blocks/CU

  const int tid = threadIdx.x;
  const int c   = blockIdx.z;
  const int x0  = blockIdx.x * TW;
  const int y0  = blockIdx.y * TH;
  const float* s = src + (size_t)c * IMG * IMG;

  // ---- stage (float4 chunks, swizzled writes) ----
  const bool xwrap = (x0 < HALO) || (x0 + TW + HALO > IMG);
  for (int ci = tid; ci < SH * CHUNKS; ci += 256) {
    int r  = ci / CHUNKS;
    int cj = ci - r * CHUNKS;
    int gy = (y0 + r - HALO) & (IMG - 1);
    int col  = 4 * cj;
    int scol = col ^ (((r >> 2) & 7) << 2);
    float4 v;
    if (!xwrap) {
      v = *reinterpret_cast<const float4*>(&s[(size_t)gy * IMG + (x0 - HALO + col)]);
    } else {
      int gx = x0 - HALO + col;
      v.x = s[(size_t)gy * IMG + ((gx + 0) & (IMG - 1))];
      v.y = s[(size_t)gy * IMG + ((gx + 1) & (IMG - 1))];
      v.z = s[(size_t)gy * IMG + ((gx + 2) & (IMG - 1))];
      v.w = s[(size_t)gy * IMG + ((gx + 3) & (IMG - 1))];
    }
    *reinterpret_cast<float4*>(&tile[r][scol]) = v;
  }
  __syncthreads();

  const int tx    = tid & 15;
  const int tyt   = tid >> 4;         // 0..15
  const int ox    = tx * 8;
  const int rbase = tyt * 4;          // this thread's first output row (local)

  float acc[4][8];
#pragma unroll
  for (int dy = 0; dy < 4; ++dy)
#pragma unroll
    for (int o = 0; o < 8; ++o) acc[dy][o] = 0.f;

#define LOADSTRIP(BUF, R)                                                     \
  do {                                                                        \
    const int _r   = (R);                                                     \
    const int _swz = ((_r >> 2) & 7) << 2;                                    \
    _Pragma("unroll")                                                         \
    for (int j = 0; j < 8; ++j)                                               \
      BUF[j] = *reinterpret_cast<const float4*>(&tile[_r][(ox + 4 * j) ^ _swz]); \
  } while (0)

#define DOFMA(BUF, RR)                                                        \
  do {                                                                        \
    const float* _row = reinterpret_cast<const float*>(BUF);                  \
    const int _rr = (RR);                                                     \
    _Pragma("unroll")                                                         \
    for (int dy = 0; dy < 4; ++dy) {                                          \
      const int _ky = _rr - dy;                                               \
      if (_ky >= 0 && _ky < KS) {                                             \
        _Pragma("unroll")                                                     \
        for (int kx = 0; kx < KS; ++kx) {                                     \
          float _w = FLIP ? kwp[(KS - 1 - _ky) * KS + (KS - 1 - kx)]          \
                          : kwp[_ky * KS + kx];                               \
          _Pragma("unroll")                                                   \
          for (int o = 0; o < 8; ++o)                                         \
            acc[dy][o] = fmaf(_w, _row[kx + o], acc[dy][o]);                  \
        }                                                                     \
      }                                                                       \
    }                                                                         \
  } while (0)

  float4 bufA[8], bufB[8];
  LOADSTRIP(bufA, rbase);
#pragma unroll 1
  for (int rr = 0; rr < NSTRIP; rr += 2) {   // NSTRIP = 28, even
    LOADSTRIP(bufB, rbase + rr + 1);
    DOFMA(bufA, rr);
    if (rr + 2 < NSTRIP) LOADSTRIP(bufA, rbase + rr + 2);
    DOFMA(bufB, rr + 1);
  }
#undef LOADSTRIP
#undef DOFMA

  float* d0 = dst + (size_t)c * IMG * IMG + (size_t)(y0 + rbase) * IMG + x0 + ox;
#pragma unroll
  for (int dy = 0; dy < 4; ++dy) {
    *reinterpret_cast<float4*>(d0 + (size_t)dy * IMG) =
        make_float4(acc[dy][0], acc[dy][1], acc[dy][2], acc[dy][3]);
    *reinterpret_cast<float4*>(d0 + (size_t)dy * IMG + 4) =
        make_float4(acc[dy][4], acc[dy][5], acc[dy][6], acc[dy][7]);
  }
}

// ---------------------------------------------------------------------------
// Separable bicubic resize passes (unchanged)
// ---------------------------------------------------------------------------
__global__ void rows_down(const float* __restrict__ src, float* __restrict__ dst,
                          const float* __restrict__ wW, const int* __restrict__ wI) {
  int x = blockIdx.x * blockDim.x + threadIdx.x;
  int o = blockIdx.y;
  int c = blockIdx.z;
  const float* s = src + (size_t)c * IMG * IMG;
  float acc = 0.f;
#pragma unroll
  for (int p = 0; p < PD; ++p)
    acc = fmaf(wW[o * PD + p], s[(size_t)wI[o * PD + p] * IMG + x], acc);
  dst[((size_t)c * DN + o) * IMG + x] = acc;
}

__global__ void cols_down(const float* __restrict__ src, float* __restrict__ dst,
                          const float* __restrict__ wW, const int* __restrict__ wI) {
  int o = blockIdx.x * blockDim.x + threadIdx.x;
  int y = blockIdx.y;
  int c = blockIdx.z;
  const float* s = src + ((size_t)c * DN + y) * IMG;
  float acc = 0.f;
#pragma unroll
  for (int p = 0; p < PD; ++p)
    acc = fmaf(wW[o * PD + p], s[wI[o * PD + p]], acc);
  dst[((size_t)c * DN + y) * DN + o] = acc;
}

__global__ void rows_up(const float* __restrict__ src, float* __restrict__ dst,
                        const float* __restrict__ wW, const int* __restrict__ wI) {
  int x = blockIdx.x * blockDim.x + threadIdx.x;
  int o = blockIdx.y;
  int c = blockIdx.z;
  const float* s = src + (size_t)c * DN * DN;
  float acc = 0.f;
#pragma unroll
  for (int p = 0; p < PU; ++p)
    acc = fmaf(wW[o * PU + p], s[(size_t)wI[o * PU + p] * DN + x], acc);
  dst[((size_t)c * IMG + o) * DN + x] = acc;
}

__global__ void cols_up_add(const float* __restrict__ src, float* __restrict__ out,
                            const float* __restrict__ wW, const int* __restrict__ wI) {
  int x = blockIdx.x * blockDim.x + threadIdx.x;
  int y = blockIdx.y;
  int c = blockIdx.z;
  const float* s = src + ((size_t)c * IMG + y) * DN;
  float acc = 0.f;
#pragma unroll
  for (int p = 0; p < PU; ++p)
    acc = fmaf(wW[x * PU + p], s[wI[x * PU + p]], acc);
  size_t oi = ((size_t)c * IMG + y) * IMG + x;
  out[oi] = fmaf(LAM, acc, out[oi]);
}

// ---------------------------------------------------------------------------
extern "C" void kernel_launch(void* const* d_in, const int* in_sizes, int n_in,
                              void* d_out, int out_size, void* d_ws, size_t ws_size,
                              hipStream_t stream) {
  const float* im  = (const float*)d_in[0];
  const float* ker = (const float*)d_in[1];
  float* out = (float*)d_out;
  float* ws  = (float*)d_ws;

  const size_t NIM = (size_t)CH * IMG * IMG;

  // ws layout (proven footprint ~50.5 MB):
  //   [0, NIM)   : ax (pass A output) -- later reused for t1/t2/t3
  //   [NIM, ...) : weight tables
  float* ax = ws;
  float* t1 = ws;
  float* t2 = t1 + (size_t)CH * DN * IMG;
  float* t3 = t2 + (size_t)CH * DN * DN;
  float* dwW = ws + NIM;
  int*   dwI = (int*)(dwW + DN * PD);
  float* uwW = (float*)(dwI + DN * PD);
  int*   uwI = (int*)(uwW + (size_t)IMG * PU);

  build_tables<<<(IMG + 255) / 256, 256, 0, stream>>>(dwW, dwI, uwW, uwI);

  // A^T A x: two 25x25 circular correlations (flipped, then plain)
  dim3 cgrid(IMG / 128, IMG / 64, CH);
  corr25<1><<<cgrid, 256, 0, stream>>>(im, ker, ax);
  corr25<0><<<cgrid, 256, 0, stream>>>(ax, ker, out);

  // 0.1 * H^T H x: 4 separable bicubic passes, accumulate into out
  rows_down  <<<dim3(IMG / 256, DN,  CH), 256, 0, stream>>>(im, t1, dwW, dwI);
  cols_down  <<<dim3(DN  / 256, DN,  CH), 256, 0, stream>>>(t1, t2, dwW, dwI);
  rows_up    <<<dim3(DN  / 256, IMG, CH), 256, 0, stream>>>(t2, t3, uwW, uwI);
  cols_up_add<<<dim3(IMG / 256, IMG, CH), 256, 0, stream>>>(t3, out, uwW, uwI);
}